// Round 4
// baseline (472.848 us; speedup 1.0000x reference)
//
#include <hip/hip_runtime.h>

// x: (64,3,512,512) fp32 -> conv3x3 VALID + avgpool2x2 + sigmoid + per-batch sum.
// Fused stride-2 4x4 conv: w_eff[ky][kx] = 0.25*sum_{py,px in {0,1}} w[ky-py][kx-px].
//
// R3: ILP restructure. R2 was latency-bound (VALUBusy 44%, 2 waves/SIMD): one
// dependent acc chain per oc + per-oc s_load stalls. Now: 32 independent
// accumulators (16 oc x 2 cols) iterated (ic,ky)-outer/oc-inner; weights
// re-laid-out [icr][oc][kx] so each (ic,ky) is 4x s_load_dwordx16.
// fp32 VALU floor: 3.19e9 MAC / 157.3 TF = 41 us.

#define IC 3
#define OCH 16
#define HH 512
#define WW 512
#define HP 255
#define SROWS 5
#define STRIPS 51  // 51 * 5 = 255 pooled rows

__device__ __forceinline__ float fast_sigmoid(float v) {
    float e = __expf(-v);                    // v_exp_f32 (neg folds into src mod)
    return __builtin_amdgcn_rcpf(1.0f + e);  // v_rcp_f32
}

// d_ws layout: ws[(ic*4+ky)*64 + oc*4 + kx] for the 768 w_eff; ws[768+oc] = bias.
__global__ void build_weff(const float* __restrict__ w,
                           const float* __restrict__ bias,
                           float* __restrict__ ws)
{
    const int i = threadIdx.x;
    for (int idx = i; idx < IC * 4 * OCH * 4; idx += 256) {
        int kx = idx & 3;
        int oc = (idx >> 2) & 15;
        int icr = idx >> 6;           // ic*4 + ky
        int ic = icr >> 2;
        int ky = icr & 3;
        float s = 0.f;
#pragma unroll
        for (int py = 0; py < 2; ++py) {
            int r = ky - py;
            if (r < 0 || r > 2) continue;
#pragma unroll
            for (int px = 0; px < 2; ++px) {
                int c = kx - px;
                if (c < 0 || c > 2) continue;
                s += w[((oc * IC + ic) * 3 + r) * 3 + c];
            }
        }
        ws[idx] = 0.25f * s;
    }
    if (i < OCH) ws[IC * 4 * OCH * 4 + i] = bias[i];
}

__global__ __launch_bounds__(128, 4)
void conv_pool_sig_sum(const float* __restrict__ x,
                       const float* __restrict__ wws,
                       float* __restrict__ out)
{
    const int tid = threadIdx.x;      // 0..127 == pooled-col-pair index
    const bool v1 = (tid < 127);      // pooled col 255 doesn't exist
    const int c0 = 4 * tid;           // input col base (max 508, 16B aligned)
    const int b = blockIdx.y;
    const int hp0 = blockIdx.x * SROWS;
    const int tail = v1 ? 4 : 0;      // right edge: re-read in-bounds, masked

    const float* xb = x + ((size_t)b * IC * HH + (size_t)2 * hp0) * WW + c0;
    const float* bp = wws + IC * 4 * OCH * 4;  // bias (16 SGPRs, loop-invariant)

    float lsA = 0.f, lsB = 0.f;

#pragma unroll 1
    for (int s = 0; s < SROWS; ++s) {
        // x window for both pooled cols, all ic: 72 floats in VGPRs, loaded once.
        float4 xa[IC][4];
        float2 xt[IC][4];
#pragma unroll
        for (int ic = 0; ic < IC; ++ic) {
            const float* pr = xb + (size_t)ic * HH * WW;
#pragma unroll
            for (int r = 0; r < 4; ++r) {
                xa[ic][r] = *(const float4*)(pr + r * WW);
                xt[ic][r] = *(const float2*)(pr + r * WW + tail);
            }
        }

        // 32 independent accumulator chains (16 oc x 2 pooled cols).
        float accA[OCH], accB[OCH];
#pragma unroll
        for (int oc = 0; oc < OCH; ++oc) { accA[oc] = bp[oc]; accB[oc] = bp[oc]; }

#pragma unroll
        for (int icr = 0; icr < IC * 4; ++icr) {
            const int ic = icr >> 2, r = icr & 3;
            const float4 a = xa[ic][r];
            const float2 t = xt[ic][r];
            const float* wp = wws + icr * 64;  // 64 uniform floats -> s_load_dwordx16 x4
#pragma unroll
            for (int oc = 0; oc < OCH; ++oc) {
                const float w0 = wp[4 * oc + 0], w1 = wp[4 * oc + 1];
                const float w2 = wp[4 * oc + 2], w3 = wp[4 * oc + 3];
                accA[oc] += a.x * w0 + a.y * w1 + a.z * w2 + a.w * w3;
                accB[oc] += a.z * w0 + a.w * w1 + t.x * w2 + t.y * w3;
            }
        }

#pragma unroll
        for (int oc = 0; oc < OCH; ++oc) {
            lsA += fast_sigmoid(accA[oc]);
            lsB += fast_sigmoid(accB[oc]);
        }
        xb += 2 * WW;
    }
    lsA += v1 ? lsB : 0.f;

    // wave64 butterfly, one atomic per wave (2 per block)
#pragma unroll
    for (int off = 32; off > 0; off >>= 1)
        lsA += __shfl_xor(lsA, off, 64);
    if ((tid & 63) == 0) atomicAdd(out + b, lsA);
}

extern "C" void kernel_launch(void* const* d_in, const int* in_sizes, int n_in,
                              void* d_out, int out_size, void* d_ws, size_t ws_size,
                              hipStream_t stream) {
    const float* x = (const float*)d_in[0];
    const float* w = (const float*)d_in[1];
    const float* bias = (const float*)d_in[2];
    float* out = (float*)d_out;
    float* wws = (float*)d_ws;  // 784 floats ~ 3.1 KB

    hipMemsetAsync(out, 0, out_size * sizeof(float), stream);
    build_weff<<<1, 256, 0, stream>>>(w, bias, wws);

    dim3 grid(STRIPS, 64);  // 51 row-strips x 64 batches = 3264 blocks
    conv_pool_sig_sum<<<grid, 128, 0, stream>>>(x, wws, out);
}

// Round 5
// 391.195 us; speedup vs baseline: 1.2087x; 1.2087x over previous
//
#include <hip/hip_runtime.h>

// x: (64,3,512,512) fp32 -> conv3x3 VALID + avgpool2x2 + sigmoid + per-batch sum.
// Fused stride-2 4x4 conv: w_eff[ky][kx] = 0.25*sum_{py,px in {0,1}} w[ky-py][kx-px].
//
// R4: keep R3's 32 independent accumulator chains (ILP win, VALUBusy 44->67%),
// but stream x loads inside the icr loop (live set 32 acc + ~6 x floats) and
// drop the launch_bounds VGPR cap -- R3's cap at 128 VGPR spilled the 72-float
// x window to scratch (VGPR_Count 44, WRITE_SIZE 42 MB, dur 2x).

#define IC 3
#define OCH 16
#define HH 512
#define WW 512
#define HP 255
#define SROWS 5
#define STRIPS 51  // 51 * 5 = 255 pooled rows

__device__ __forceinline__ float fast_sigmoid(float v) {
    float e = __expf(-v);                    // v_exp_f32 (neg folds into src mod)
    return __builtin_amdgcn_rcpf(1.0f + e);  // v_rcp_f32
}

// d_ws layout: ws[(ic*4+ky)*64 + oc*4 + kx] for the 768 w_eff; ws[768+oc] = bias.
__global__ void build_weff(const float* __restrict__ w,
                           const float* __restrict__ bias,
                           float* __restrict__ ws)
{
    const int i = threadIdx.x;
    for (int idx = i; idx < IC * 4 * OCH * 4; idx += 256) {
        int kx = idx & 3;
        int oc = (idx >> 2) & 15;
        int icr = idx >> 6;           // ic*4 + ky
        int ic = icr >> 2;
        int ky = icr & 3;
        float s = 0.f;
#pragma unroll
        for (int py = 0; py < 2; ++py) {
            int r = ky - py;
            if (r < 0 || r > 2) continue;
#pragma unroll
            for (int px = 0; px < 2; ++px) {
                int c = kx - px;
                if (c < 0 || c > 2) continue;
                s += w[((oc * IC + ic) * 3 + r) * 3 + c];
            }
        }
        ws[idx] = 0.25f * s;
    }
    if (i < OCH) ws[IC * 4 * OCH * 4 + i] = bias[i];
}

__global__ __launch_bounds__(128)
void conv_pool_sig_sum(const float* __restrict__ x,
                       const float* __restrict__ wws,
                       float* __restrict__ out)
{
    const int tid = threadIdx.x;      // 0..127 == pooled-col-pair index
    const bool v1 = (tid < 127);      // pooled col 255 doesn't exist
    const int c0 = 4 * tid;           // input col base (max 508, 16B aligned)
    const int b = blockIdx.y;
    const int hp0 = blockIdx.x * SROWS;
    const int tail = v1 ? 4 : 0;      // right edge: re-read in-bounds, masked

    const float* xb = x + ((size_t)b * IC * HH + (size_t)2 * hp0) * WW + c0;
    const float* bp = wws + IC * 4 * OCH * 4;  // bias (uniform -> SGPRs)

    float lsA = 0.f, lsB = 0.f;

#pragma unroll 1
    for (int s = 0; s < SROWS; ++s) {
        // 32 independent accumulator chains (16 oc x 2 pooled cols).
        float accA[OCH], accB[OCH];
#pragma unroll
        for (int oc = 0; oc < OCH; ++oc) { accA[oc] = bp[oc]; accB[oc] = bp[oc]; }

        // Stream the 12 (ic, window-row) x-loads: only ~6 x floats live at once,
        // compiler pipelines the loads across the unrolled icr iterations.
#pragma unroll
        for (int icr = 0; icr < IC * 4; ++icr) {
            const int ic = icr >> 2, r = icr & 3;
            const float* pr = xb + (size_t)ic * HH * WW + r * WW;
            const float4 a = *(const float4*)pr;          // cols c0..c0+3
            const float2 t = *(const float2*)(pr + tail); // cols c0+4..c0+5
            const float* wp = wws + icr * 64;  // uniform -> s_load_dwordx16 x4
#pragma unroll
            for (int oc = 0; oc < OCH; ++oc) {
                const float w0 = wp[4 * oc + 0], w1 = wp[4 * oc + 1];
                const float w2 = wp[4 * oc + 2], w3 = wp[4 * oc + 3];
                accA[oc] += a.x * w0 + a.y * w1 + a.z * w2 + a.w * w3;
                accB[oc] += a.z * w0 + a.w * w1 + t.x * w2 + t.y * w3;
            }
        }

#pragma unroll
        for (int oc = 0; oc < OCH; ++oc) {
            lsA += fast_sigmoid(accA[oc]);
            lsB += fast_sigmoid(accB[oc]);
        }
        xb += 2 * WW;
    }
    lsA += v1 ? lsB : 0.f;

    // wave64 butterfly, one atomic per wave (2 per block)
#pragma unroll
    for (int off = 32; off > 0; off >>= 1)
        lsA += __shfl_xor(lsA, off, 64);
    if ((tid & 63) == 0) atomicAdd(out + b, lsA);
}

extern "C" void kernel_launch(void* const* d_in, const int* in_sizes, int n_in,
                              void* d_out, int out_size, void* d_ws, size_t ws_size,
                              hipStream_t stream) {
    const float* x = (const float*)d_in[0];
    const float* w = (const float*)d_in[1];
    const float* bias = (const float*)d_in[2];
    float* out = (float*)d_out;
    float* wws = (float*)d_ws;  // 784 floats ~ 3.1 KB

    hipMemsetAsync(out, 0, out_size * sizeof(float), stream);
    build_weff<<<1, 256, 0, stream>>>(w, bias, wws);

    dim3 grid(STRIPS, 64);  // 51 row-strips x 64 batches = 3264 blocks
    conv_pool_sig_sum<<<grid, 128, 0, stream>>>(x, wws, out);
}